// Round 12
// baseline (170.794 us; speedup 1.0000x reference)
//
#include <hip/hip_runtime.h>
#include <hip/hip_bf16.h>

#define BB  8
#define CC  128
#define LXX 4096
#define LYY 1024
#define HH  4
#define DHH 32

typedef __attribute__((ext_vector_type(8))) short bf16x8;
typedef __attribute__((ext_vector_type(4))) float f32x4;

static __device__ __forceinline__ unsigned short f2bf(float f) {
    __hip_bfloat16 h = __float2bfloat16(f);
    return *reinterpret_cast<unsigned short*>(&h);
}

static __device__ __forceinline__ bf16x8 pack8(const float* f) {
    bf16x8 r;
#pragma unroll
    for (int i = 0; i < 8; ++i) {
        __hip_bfloat16 h = __float2bfloat16(f[i]);
        r[i] = *reinterpret_cast<short*>(&h);
    }
    return r;
}

// load 8 consecutive f32 weights -> one MFMA A-fragment (bf16)
static __device__ __forceinline__ bf16x8 ldw8(const float* p) {
    float t[8];
    *(float4*)(t)     = *(const float4*)(p);
    *(float4*)(t + 4) = *(const float4*)(p + 4);
    return pack8(t);
}

// ============== single kernel: kproj-unit || Q-proj/conv, release/acquire, attn ==============
// R12: R11's overlay redone with graph-safe primitives (cooperative launch
// doesn't execute under graph capture -> R11 output was all zeros).
// Deadlock-free by construction: grid 1024 = 4 blocks/CU (launch_bounds
// (256,4); LDS 28.3KB -> 5/CU; VGPR 60) -> ENTIRE grid co-resident, so the
// spin always terminates regardless of dispatch order (G16-safe).
// Per block: (1) one of 1024 kproj units (fb = bik x l0k x m, same rounding
// path as R10's kproj); (2) syncthreads + tid0 RELEASE atomicAdd (wbl2 ->
// K visible device-wide); (3) Q-prologue (R10 dedup'd LDS staging; weight
// cvt hidden between signal and wait -> R7's +14us exposure avoided);
// (4) tid0 ACQUIRE spin (invalidates stale poison lines in this XCD's
// L2/L1) until 1024; (5) unchanged attn phases.
// MEASURED DEAD ENDS — do not retry: (R1) launch_bounds(512,8) cap ->
// 1.1 GB scratch spill; (R2) kernel-split softmax -> +15 us; (R4) 8-wave/
// 128-key -> +35% VALU; (R6) m-split proj -> dup staging +8 us; (R9)
// load-hoist under 128-reg cap -> neutral; (R11) hipLaunchCooperativeKernel
// -> silently no-op under graph capture.
__global__ __launch_bounds__(256, 4) void fused_all_kernel(
    const float* __restrict__ x, const float* __restrict__ y,
    const float* __restrict__ ipw, const float* __restrict__ ipb,
    const float* __restrict__ c1w, const float* __restrict__ c1b,
    const float* __restrict__ c2w, const float* __restrict__ c2b,
    const float* __restrict__ gw, const float* __restrict__ gb,
    unsigned short* __restrict__ Kb, unsigned int* __restrict__ done,
    float* __restrict__ out, float qscale)
{
    int tid = threadIdx.x;
    int w = tid >> 6;           // wave: key quarter AND Q-proj m-pair owner
    int lane = tid & 63;
    int n16 = lane & 15;
    int quad = lane >> 4;
    int bi = blockIdx.y;
    int q0 = blockIdx.x * 32;
    int fb = bi * 128 + blockIdx.x;   // flat block id 0..1023

    __shared__ float xls[32][132];               // [l_rel][c] f32, 16.9 KB
    __shared__ unsigned short qlds[2][16][136];  // [qt][l][d], stride 136
    __shared__ float dlds[4][2][HH][16];
    __shared__ float mlds[4][2][16];
    __shared__ float plds[32];

    const f32x4 fzero = {0.f, 0.f, 0.f, 0.f};

    // ---- (1) this block's kproj unit: fb -> (bik, l0k, m) ----
    {
        int bik = fb >> 7;
        int l0k = ((fb >> 3) & 15) * 64;
        int m   = fb & 7;
        const float* srcK  = y + (size_t)bik * CC * LYY;
        const float* wrow  = ipw + CC * CC;
        const float* biasK = ipb + CC;
        int mylK = l0k + w * 16 + n16;

        bf16x8 bfrK[4];
#pragma unroll
        for (int kk = 0; kk < 4; ++kk) {
            float t[8];
            const float* p = srcK + (size_t)(kk * 32 + quad * 8) * LYY + mylK;
#pragma unroll
            for (int j = 0; j < 8; ++j) t[j] = p[(size_t)j * LYY];
            bfrK[kk] = pack8(t);
        }
        int mc = m * 16;
        f32x4 acc = fzero;
#pragma unroll
        for (int kk = 0; kk < 4; ++kk)
            acc = __builtin_amdgcn_mfma_f32_16x16x32_bf16(
                ldw8(wrow + (size_t)(mc + n16) * CC + kk * 32 + quad * 8),
                bfrK[kk], acc, 0, 0, 0);
        int h = mc >> 5, d0 = (mc & 31) + quad * 4;
        float4 bq4 = *(const float4*)(biasK + mc + quad * 4);
        ushort4 u;
        u.x = f2bf(acc[0] + bq4.x);
        u.y = f2bf(acc[1] + bq4.y);
        u.z = f2bf(acc[2] + bq4.z);
        u.w = f2bf(acc[3] + bq4.w);
        *(ushort4*)(Kb + (((size_t)(bik * HH + h) * LYY) + mylK) * DHH + d0) = u;
    }

    // ---- (2) signal: stores drained by syncthreads, release-add flushes L2 ----
    __syncthreads();
    if (tid == 0)
        __hip_atomic_fetch_add(done, 1u, __ATOMIC_RELEASE, __HIP_MEMORY_SCOPE_AGENT);

    // ---- (3) Q-proj + conv prologue (runs while other blocks finish kproj) ----
    const float* xsrc = x + (size_t)bi * CC * LXX;
#pragma unroll
    for (int i = 0; i < 4; ++i) {
        int idx = i * 256 + tid;
        int c  = idx >> 3;
        int l4 = (idx & 7) * 4;
        float4 v = *(const float4*)(xsrc + (size_t)c * LXX + q0 + l4);
        xls[l4 + 0][c] = v.x;
        xls[l4 + 1][c] = v.y;
        xls[l4 + 2][c] = v.z;
        xls[l4 + 3][c] = v.w;
    }
    bf16x8 wf[2][4];
#pragma unroll
    for (int mi = 0; mi < 2; ++mi)
#pragma unroll
        for (int kk = 0; kk < 4; ++kk)
            wf[mi][kk] = ldw8(ipw + (size_t)((2 * w + mi) * 16 + n16) * CC + kk * 32 + quad * 8);
    __syncthreads();

    bf16x8 bq[2][4];
#pragma unroll
    for (int qt = 0; qt < 2; ++qt)
#pragma unroll
        for (int kk = 0; kk < 4; ++kk) {
            float t[8];
            *(float4*)(t)     = *(const float4*)(&xls[qt * 16 + n16][kk * 32 + quad * 8]);
            *(float4*)(t + 4) = *(const float4*)(&xls[qt * 16 + n16][kk * 32 + quad * 8 + 4]);
            bq[qt][kk] = pack8(t);
        }

#pragma unroll
    for (int qt = 0; qt < 2; ++qt) {
#pragma unroll
        for (int mi = 0; mi < 2; ++mi) {
            int m = 2 * w + mi;
            f32x4 acc = fzero;
#pragma unroll
            for (int kk = 0; kk < 4; ++kk)
                acc = __builtin_amdgcn_mfma_f32_16x16x32_bf16(wf[mi][kk], bq[qt][kk], acc, 0, 0, 0);
            float4 bv = *(const float4*)(ipb + m * 16 + quad * 4);
            ushort4 u;
            u.x = f2bf((acc[0] + bv.x) * qscale);
            u.y = f2bf((acc[1] + bv.y) * qscale);
            u.z = f2bf((acc[2] + bv.z) * qscale);
            u.w = f2bf((acc[3] + bv.w) * qscale);
            *(ushort4*)(&qlds[qt][n16][m * 16 + quad * 4]) = u;
        }
        if (w == 2 + qt) {
            float p = 0.f;
#pragma unroll
            for (int m2 = 0; m2 < 2; ++m2) {
                f32x4 hacc = fzero;
#pragma unroll
                for (int kk = 0; kk < 4; ++kk)
                    hacc = __builtin_amdgcn_mfma_f32_16x16x32_bf16(
                        ldw8(c1w + (size_t)(m2 * 16 + n16) * CC + kk * 32 + quad * 8),
                        bq[qt][kk], hacc, 0, 0, 0);
#pragma unroll
                for (int r = 0; r < 4; ++r) {
                    int o = m2 * 16 + quad * 4 + r;
                    p = fmaf(c2w[o], fmaxf(hacc[r] + c1b[o], 0.0f), p);
                }
            }
            p += __shfl_xor(p, 16, 64);
            p += __shfl_xor(p, 32, 64);
            if (quad == 0)
                plds[qt * 16 + n16] = 1.0f / (1.0f + __expf(-(p + c2b[0])));
        }
    }
    __syncthreads();

    bf16x8 afr[2][HH];
#pragma unroll
    for (int qt = 0; qt < 2; ++qt)
#pragma unroll
        for (int h = 0; h < HH; ++h)
            afr[qt][h] = *(const bf16x8*)(&qlds[qt][n16][h * 32 + quad * 8]);

    // ---- (4) wait for all 1024 kproj units; acquire invalidates stale lines ----
    if (tid == 0) {
        while (__hip_atomic_load(done, __ATOMIC_ACQUIRE, __HIP_MEMORY_SCOPE_AGENT) < 1024u)
            __builtin_amdgcn_s_sleep(8);
    }
    __syncthreads();

    const unsigned short* Kbase = Kb + (((size_t)bi * HH) * LYY + w * 256 + n16) * DHH + quad * 8;

    // ---- phase 1: denominators over this wave's 256 keys ----
    f32x4 den[2][HH];
#pragma unroll
    for (int qt = 0; qt < 2; ++qt)
#pragma unroll
        for (int h = 0; h < HH; ++h) den[qt][h] = fzero;

#pragma unroll 2
    for (int t = 0; t < 16; ++t) {
        bf16x8 bfr[HH];
#pragma unroll
        for (int h = 0; h < HH; ++h)
            bfr[h] = *(const bf16x8*)(Kbase + ((size_t)h * LYY + t * 16) * DHH);
#pragma unroll
        for (int h = 0; h < HH; ++h) {
            f32x4 s0 = __builtin_amdgcn_mfma_f32_16x16x32_bf16(afr[0][h], bfr[h], fzero, 0, 0, 0);
            f32x4 s1 = __builtin_amdgcn_mfma_f32_16x16x32_bf16(afr[1][h], bfr[h], fzero, 0, 0, 0);
#pragma unroll
            for (int r = 0; r < 4; ++r) {
                den[0][h][r] += __builtin_amdgcn_exp2f(s0[r]);
                den[1][h][r] += __builtin_amdgcn_exp2f(s1[r]);
            }
        }
    }
#pragma unroll
    for (int off = 1; off < 16; off <<= 1)
#pragma unroll
        for (int qt = 0; qt < 2; ++qt)
#pragma unroll
            for (int h = 0; h < HH; ++h)
#pragma unroll
                for (int r = 0; r < 4; ++r)
                    den[qt][h][r] += __shfl_xor(den[qt][h][r], off, 64);
    if (n16 == 0) {
#pragma unroll
        for (int qt = 0; qt < 2; ++qt)
#pragma unroll
            for (int h = 0; h < HH; ++h)
#pragma unroll
                for (int r = 0; r < 4; ++r) dlds[w][qt][h][quad * 4 + r] = den[qt][h][r];
    }
    __syncthreads();

    // c = -log2(total den)
    f32x4 cc[2][HH];
#pragma unroll
    for (int qt = 0; qt < 2; ++qt)
#pragma unroll
        for (int h = 0; h < HH; ++h)
#pragma unroll
            for (int r = 0; r < 4; ++r) {
                int row = quad * 4 + r;
                float d = dlds[0][qt][h][row] + dlds[1][qt][h][row] +
                          dlds[2][qt][h][row] + dlds[3][qt][h][row];
                cc[qt][h][r] = -__builtin_amdgcn_logf(d);
            }

    // ---- phase 2: f(k) = sum_h exp2(s + c_h); running key-max ----
    f32x4 vm0 = fzero, vm1 = fzero;
#pragma unroll 2
    for (int t = 0; t < 16; ++t) {
        bf16x8 bfr[HH];
#pragma unroll
        for (int h = 0; h < HH; ++h)
            bfr[h] = *(const bf16x8*)(Kbase + ((size_t)h * LYY + t * 16) * DHH);
        f32x4 f0 = fzero, f1 = fzero;
#pragma unroll
        for (int h = 0; h < HH; ++h) {
            f32x4 s0 = __builtin_amdgcn_mfma_f32_16x16x32_bf16(afr[0][h], bfr[h], cc[0][h], 0, 0, 0);
            f32x4 s1 = __builtin_amdgcn_mfma_f32_16x16x32_bf16(afr[1][h], bfr[h], cc[1][h], 0, 0, 0);
#pragma unroll
            for (int r = 0; r < 4; ++r) {
                f0[r] += __builtin_amdgcn_exp2f(s0[r]);
                f1[r] += __builtin_amdgcn_exp2f(s1[r]);
            }
        }
#pragma unroll
        for (int r = 0; r < 4; ++r) {
            vm0[r] = fmaxf(vm0[r], f0[r]);
            vm1[r] = fmaxf(vm1[r], f1[r]);
        }
    }
#pragma unroll
    for (int off = 1; off < 16; off <<= 1)
#pragma unroll
        for (int r = 0; r < 4; ++r) {
            vm0[r] = fmaxf(vm0[r], __shfl_xor(vm0[r], off, 64));
            vm1[r] = fmaxf(vm1[r], __shfl_xor(vm1[r], off, 64));
        }
    if (n16 == 0) {
#pragma unroll
        for (int r = 0; r < 4; ++r) {
            mlds[w][0][quad * 4 + r] = vm0[r];
            mlds[w][1][quad * 4 + r] = vm1[r];
        }
    }
    __syncthreads();
    if (tid < 32) {
        int qq = tid >> 4;
        int row = tid & 15;
        float m = fmaxf(fmaxf(mlds[0][qq][row], mlds[1][qq][row]),
                        fmaxf(mlds[2][qq][row], mlds[3][qq][row]));
        float cs = 0.25f * m;
        int orow = q0 + qq * 16 + row;
        float ls = plds[qq * 16 + row];
        float z = gw[0] * cs + gw[1] * ls + gb[0];
        float alpha = 1.0f / (1.0f + __expf(-z));
        out[(size_t)bi * LXX + orow] = alpha * cs + (1.0f - alpha) * ls;
    }
}

extern "C" void kernel_launch(void* const* d_in, const int* in_sizes, int n_in,
                              void* d_out, int out_size, void* d_ws, size_t ws_size,
                              hipStream_t stream) {
    const float* x   = (const float*)d_in[0];
    const float* y   = (const float*)d_in[1];
    const float* ipw = (const float*)d_in[2];
    const float* ipb = (const float*)d_in[3];
    const float* c1w = (const float*)d_in[4];
    const float* c1b = (const float*)d_in[5];
    const float* c2w = (const float*)d_in[6];
    const float* c2b = (const float*)d_in[7];
    const float* gw  = (const float*)d_in[8];
    const float* gb  = (const float*)d_in[9];
    float* out = (float*)d_out;

    unsigned short* Kb = (unsigned short*)d_ws;              // 2 MB bf16 K
    unsigned int* done = (unsigned int*)(Kb + (size_t)BB * HH * LYY * DHH);

    // zero the completion counter each iteration (ws is poison-filled by the
    // harness before every replay; 4-byte memset is graph-capturable)
    hipMemsetAsync(done, 0, sizeof(unsigned int), stream);

    // 1/sqrt(32) * log2(e): exp2-domain softmax, folded into Q only
    const float qscale = 0.17677669529663687f * 1.4426950408889634f;

    hipLaunchKernelGGL(fused_all_kernel, dim3(LXX / 32, BB), dim3(256), 0, stream,
                       x, y, ipw, ipb, c1w, c1b, c2w, c2b, gw, gb,
                       Kb, done, out, qscale);
}

// Round 13
// 128.571 us; speedup vs baseline: 1.3284x; 1.3284x over previous
//
#include <hip/hip_runtime.h>
#include <hip/hip_bf16.h>

#define BB  8
#define CC  128
#define LXX 4096
#define LYY 1024
#define HH  4
#define DHH 32

typedef __attribute__((ext_vector_type(8))) short bf16x8;
typedef __attribute__((ext_vector_type(4))) float f32x4;

static __device__ __forceinline__ unsigned short f2bf(float f) {
    __hip_bfloat16 h = __float2bfloat16(f);
    return *reinterpret_cast<unsigned short*>(&h);
}

static __device__ __forceinline__ bf16x8 pack8(const float* f) {
    bf16x8 r;
#pragma unroll
    for (int i = 0; i < 8; ++i) {
        __hip_bfloat16 h = __float2bfloat16(f[i]);
        r[i] = *reinterpret_cast<short*>(&h);
    }
    return r;
}

// load 8 consecutive f32 weights -> one MFMA A-fragment (bf16)
static __device__ __forceinline__ bf16x8 ldw8(const float* p) {
    float t[8];
    *(float4*)(t)     = *(const float4*)(p);
    *(float4*)(t + 4) = *(const float4*)(p + 4);
    return pack8(t);
}

// ================= K projection + weight prepack (one launch) =================
// blocks 0..255: K-proj, m-split (m 0..3 / 4..7), 1 block/CU.
// blocks 256..271: prepack wbf = bf16{Wq, Wk, conv1_w} for attn's prologue.
__global__ __launch_bounds__(256) void kproj_pre_kernel(
    const float* __restrict__ y, const float* __restrict__ ipw,
    const float* __restrict__ ipb, const float* __restrict__ c1w,
    unsigned short* __restrict__ Kb, unsigned short* __restrict__ wbf)
{
    int tid  = threadIdx.x;
    int blk  = blockIdx.x;

    if (blk >= 256) {
        // ---- prepack: 16 blocks x 2304 elems ----
        int base = (blk - 256) * 2304;
#pragma unroll
        for (int j = 0; j < 9; ++j) {
            int idx = base + j * 256 + tid;
            float v = (idx < 2 * CC * CC) ? ipw[idx] : c1w[idx - 2 * CC * CC];
            wbf[idx] = f2bf(v);
        }
        return;
    }

    int wv   = tid >> 6;
    int lane = tid & 63;
    int n16  = lane & 15;
    int quad = lane >> 4;

    int bi = blk >> 5;
    int rest = blk & 31;
    int l0 = (rest >> 1) * 64;
    int mh = rest & 1;                 // m-range half: 0..3 or 4..7
    const float* src  = y + (size_t)bi * CC * LYY;
    const float* wrow = ipw + CC * CC; // Wk (f32; converted inline — same launch)
    const float* bias = ipb + CC;
    int myl = l0 + wv * 16 + n16;

    bf16x8 bfr[4];
#pragma unroll
    for (int kk = 0; kk < 4; ++kk) {
        float t[8];
        const float* p = src + (size_t)(kk * 32 + quad * 8) * LYY + myl;
#pragma unroll
        for (int j = 0; j < 8; ++j) t[j] = p[(size_t)j * LYY];
        bfr[kk] = pack8(t);
    }

    const f32x4 fzero = {0.f, 0.f, 0.f, 0.f};
#pragma unroll 1
    for (int mi = 0; mi < 4; ++mi) {
        int m = mh * 4 + mi;
        int mc = m * 16;
        f32x4 acc = fzero;
#pragma unroll
        for (int kk = 0; kk < 4; ++kk)
            acc = __builtin_amdgcn_mfma_f32_16x16x32_bf16(
                ldw8(wrow + (size_t)(mc + n16) * CC + kk * 32 + quad * 8),
                bfr[kk], acc, 0, 0, 0);
        int h = mc >> 5, d0 = (mc & 31) + quad * 4;
        float4 bq = *(const float4*)(bias + mc + quad * 4);
        ushort4 u;
        u.x = f2bf(acc[0] + bq.x);
        u.y = f2bf(acc[1] + bq.y);
        u.z = f2bf(acc[2] + bq.z);
        u.w = f2bf(acc[3] + bq.w);
        *(ushort4*)(Kb + (((size_t)(bi * HH + h) * LYY) + myl) * DHH + d0) = u;
    }
}

// ================= fully fused: Q-proj + conv + attention + gate =================
// R13 = R10 (best, 128.75us) + xls bank-conflict fix. R10's 1.8M
// SQ_LDS_BANK_CONFLICT was the xls READ side: stride 132 -> bank
// 4*n16+8*quad = 8 groups for 64 lanes = 8-way on every b128 staging read.
// Stride 133 (odd): bank 5*row+col, balanced <=2-way (free, m136) on both
// write and read; rows no longer 16B-aligned so fragment reads are explicit
// scalar ds_read_b32 (8 x 5.8cyc beats 2 x b128 at 8-way ~ 12 x 2.9cyc).
// Values bit-identical (raw f32 through LDS, same pack8/MFMA order).
// MEASURED DEAD ENDS — do not retry: (R1) launch_bounds(512,8) cap ->
// 1.1 GB scratch spill; (R2) kernel-split softmax -> +15 us; (R4) 8-wave/
// 128-key -> +35% VALU; (R6) m-split proj -> dup staging +8 us; (R7)
// per-block weight cvt -> +14 us; (R9) load-hoist under 128-reg cap ->
// neutral; (R11) cooperative launch no-ops under graph capture; (R12)
// atomic release/acquire overlay -> +42 us (straggler wait + sync traffic).
__global__ __launch_bounds__(256, 4) void attn_fused_kernel(
    const float* __restrict__ x, const unsigned short* __restrict__ Kh,
    const unsigned short* __restrict__ wbf, const float* __restrict__ ipb,
    const float* __restrict__ c1b,
    const float* __restrict__ c2w, const float* __restrict__ c2b,
    const float* __restrict__ gw, const float* __restrict__ gb,
    float* __restrict__ out, float qscale)
{
    int tid = threadIdx.x;
    int w = tid >> 6;           // wave: key quarter AND Q-proj m-pair owner
    int lane = tid & 63;
    int n16 = lane & 15;
    int quad = lane >> 4;
    int bi = blockIdx.y;
    int q0 = blockIdx.x * 32;

    __shared__ float xls[32][133];               // [l_rel][c] f32; stride 133 (odd) -> <=2-way banks
    __shared__ unsigned short qlds[2][16][136];  // [qt][l][d], stride 136
    __shared__ float dlds[4][2][HH][16];
    __shared__ float mlds[4][2][16];
    __shared__ float plds[32];

    const float* xsrc = x + (size_t)bi * CC * LXX;
    const unsigned short* wc1 = wbf + 2 * CC * CC;
    const f32x4 fzero = {0.f, 0.f, 0.f, 0.f};

    // ---- cooperative x-tile staging: 1024 float4 = 128 ch x 8 ----
#pragma unroll
    for (int i = 0; i < 4; ++i) {
        int idx = i * 256 + tid;
        int c  = idx >> 3;
        int l4 = (idx & 7) * 4;
        float4 v = *(const float4*)(xsrc + (size_t)c * LXX + q0 + l4);
        xls[l4 + 0][c] = v.x;
        xls[l4 + 1][c] = v.y;
        xls[l4 + 2][c] = v.z;
        xls[l4 + 3][c] = v.w;
    }
    // this wave's weight fragments (m = 2w, 2w+1): issued before the barrier
    bf16x8 wf[2][4];
#pragma unroll
    for (int mi = 0; mi < 2; ++mi)
#pragma unroll
        for (int kk = 0; kk < 4; ++kk)
            wf[mi][kk] = *(const bf16x8*)(wbf +
                (size_t)((2 * w + mi) * 16 + n16) * CC + kk * 32 + quad * 8);
    __syncthreads();

    // fragments from LDS: explicit scalar ds_read_b32 (conflict-free at stride 133)
    bf16x8 bq[2][4];
#pragma unroll
    for (int qt = 0; qt < 2; ++qt)
#pragma unroll
        for (int kk = 0; kk < 4; ++kk) {
            float t[8];
#pragma unroll
            for (int j = 0; j < 8; ++j)
                t[j] = xls[qt * 16 + n16][kk * 32 + quad * 8 + j];
            bq[qt][kk] = pack8(t);
        }

#pragma unroll
    for (int qt = 0; qt < 2; ++qt) {
#pragma unroll
        for (int mi = 0; mi < 2; ++mi) {
            int m = 2 * w + mi;
            f32x4 acc = fzero;
#pragma unroll
            for (int kk = 0; kk < 4; ++kk)
                acc = __builtin_amdgcn_mfma_f32_16x16x32_bf16(wf[mi][kk], bq[qt][kk], acc, 0, 0, 0);
            float4 bv = *(const float4*)(ipb + m * 16 + quad * 4);
            ushort4 u;
            u.x = f2bf((acc[0] + bv.x) * qscale);
            u.y = f2bf((acc[1] + bv.y) * qscale);
            u.z = f2bf((acc[2] + bv.z) * qscale);
            u.w = f2bf((acc[3] + bv.w) * qscale);
            *(ushort4*)(&qlds[qt][n16][m * 16 + quad * 4]) = u;
        }
        // conv for this qt's 16 rows: wave 2 -> qt 0, wave 3 -> qt 1
        if (w == 2 + qt) {
            float p = 0.f;
#pragma unroll
            for (int m2 = 0; m2 < 2; ++m2) {
                f32x4 hacc = fzero;
#pragma unroll
                for (int kk = 0; kk < 4; ++kk)
                    hacc = __builtin_amdgcn_mfma_f32_16x16x32_bf16(
                        *(const bf16x8*)(wc1 + (size_t)(m2 * 16 + n16) * CC + kk * 32 + quad * 8),
                        bq[qt][kk], hacc, 0, 0, 0);
#pragma unroll
                for (int r = 0; r < 4; ++r) {
                    int o = m2 * 16 + quad * 4 + r;
                    p = fmaf(c2w[o], fmaxf(hacc[r] + c1b[o], 0.0f), p);
                }
            }
            p += __shfl_xor(p, 16, 64);
            p += __shfl_xor(p, 32, 64);
            if (quad == 0)
                plds[qt * 16 + n16] = 1.0f / (1.0f + __expf(-(p + c2b[0])));
        }
    }
    __syncthreads();

    // afr fragments from qlds: 8x ds_read_b128
    bf16x8 afr[2][HH];
#pragma unroll
    for (int qt = 0; qt < 2; ++qt)
#pragma unroll
        for (int h = 0; h < HH; ++h)
            afr[qt][h] = *(const bf16x8*)(&qlds[qt][n16][h * 32 + quad * 8]);

    const unsigned short* Kbase = Kh + (((size_t)bi * HH) * LYY + w * 256 + n16) * DHH + quad * 8;

    // ---- phase 1: denominators over this wave's 256 keys ----
    f32x4 den[2][HH];
#pragma unroll
    for (int qt = 0; qt < 2; ++qt)
#pragma unroll
        for (int h = 0; h < HH; ++h) den[qt][h] = fzero;

#pragma unroll 2
    for (int t = 0; t < 16; ++t) {
        bf16x8 bfr[HH];
#pragma unroll
        for (int h = 0; h < HH; ++h)
            bfr[h] = *(const bf16x8*)(Kbase + ((size_t)h * LYY + t * 16) * DHH);
#pragma unroll
        for (int h = 0; h < HH; ++h) {
            f32x4 s0 = __builtin_amdgcn_mfma_f32_16x16x32_bf16(afr[0][h], bfr[h], fzero, 0, 0, 0);
            f32x4 s1 = __builtin_amdgcn_mfma_f32_16x16x32_bf16(afr[1][h], bfr[h], fzero, 0, 0, 0);
#pragma unroll
            for (int r = 0; r < 4; ++r) {
                den[0][h][r] += __builtin_amdgcn_exp2f(s0[r]);
                den[1][h][r] += __builtin_amdgcn_exp2f(s1[r]);
            }
        }
    }
#pragma unroll
    for (int off = 1; off < 16; off <<= 1)
#pragma unroll
        for (int qt = 0; qt < 2; ++qt)
#pragma unroll
            for (int h = 0; h < HH; ++h)
#pragma unroll
                for (int r = 0; r < 4; ++r)
                    den[qt][h][r] += __shfl_xor(den[qt][h][r], off, 64);
    if (n16 == 0) {
#pragma unroll
        for (int qt = 0; qt < 2; ++qt)
#pragma unroll
            for (int h = 0; h < HH; ++h)
#pragma unroll
                for (int r = 0; r < 4; ++r) dlds[w][qt][h][quad * 4 + r] = den[qt][h][r];
    }
    __syncthreads();

    // c = -log2(total den)
    f32x4 cc[2][HH];
#pragma unroll
    for (int qt = 0; qt < 2; ++qt)
#pragma unroll
        for (int h = 0; h < HH; ++h)
#pragma unroll
            for (int r = 0; r < 4; ++r) {
                int row = quad * 4 + r;
                float d = dlds[0][qt][h][row] + dlds[1][qt][h][row] +
                          dlds[2][qt][h][row] + dlds[3][qt][h][row];
                cc[qt][h][r] = -__builtin_amdgcn_logf(d);
            }

    // ---- phase 2: f(k) = sum_h exp2(s + c_h); running key-max ----
    f32x4 vm0 = fzero, vm1 = fzero;
#pragma unroll 2
    for (int t = 0; t < 16; ++t) {
        bf16x8 bfr[HH];
#pragma unroll
        for (int h = 0; h < HH; ++h)
            bfr[h] = *(const bf16x8*)(Kbase + ((size_t)h * LYY + t * 16) * DHH);
        f32x4 f0 = fzero, f1 = fzero;
#pragma unroll
        for (int h = 0; h < HH; ++h) {
            f32x4 s0 = __builtin_amdgcn_mfma_f32_16x16x32_bf16(afr[0][h], bfr[h], cc[0][h], 0, 0, 0);
            f32x4 s1 = __builtin_amdgcn_mfma_f32_16x16x32_bf16(afr[1][h], bfr[h], cc[1][h], 0, 0, 0);
#pragma unroll
            for (int r = 0; r < 4; ++r) {
                f0[r] += __builtin_amdgcn_exp2f(s0[r]);
                f1[r] += __builtin_amdgcn_exp2f(s1[r]);
            }
        }
#pragma unroll
        for (int r = 0; r < 4; ++r) {
            vm0[r] = fmaxf(vm0[r], f0[r]);
            vm1[r] = fmaxf(vm1[r], f1[r]);
        }
    }
#pragma unroll
    for (int off = 1; off < 16; off <<= 1)
#pragma unroll
        for (int r = 0; r < 4; ++r) {
            vm0[r] = fmaxf(vm0[r], __shfl_xor(vm0[r], off, 64));
            vm1[r] = fmaxf(vm1[r], __shfl_xor(vm1[r], off, 64));
        }
    if (n16 == 0) {
#pragma unroll
        for (int r = 0; r < 4; ++r) {
            mlds[w][0][quad * 4 + r] = vm0[r];
            mlds[w][1][quad * 4 + r] = vm1[r];
        }
    }
    __syncthreads();
    if (tid < 32) {
        int qq = tid >> 4;
        int row = tid & 15;
        float m = fmaxf(fmaxf(mlds[0][qq][row], mlds[1][qq][row]),
                        fmaxf(mlds[2][qq][row], mlds[3][qq][row]));
        float cs = 0.25f * m;
        int orow = q0 + qq * 16 + row;
        float ls = plds[qq * 16 + row];
        float z = gw[0] * cs + gw[1] * ls + gb[0];
        float alpha = 1.0f / (1.0f + __expf(-z));
        out[(size_t)bi * LXX + orow] = alpha * cs + (1.0f - alpha) * ls;
    }
}

extern "C" void kernel_launch(void* const* d_in, const int* in_sizes, int n_in,
                              void* d_out, int out_size, void* d_ws, size_t ws_size,
                              hipStream_t stream) {
    const float* x   = (const float*)d_in[0];
    const float* y   = (const float*)d_in[1];
    const float* ipw = (const float*)d_in[2];
    const float* ipb = (const float*)d_in[3];
    const float* c1w = (const float*)d_in[4];
    const float* c1b = (const float*)d_in[5];
    const float* c2w = (const float*)d_in[6];
    const float* c2b = (const float*)d_in[7];
    const float* gw  = (const float*)d_in[8];
    const float* gb  = (const float*)d_in[9];
    float* out = (float*)d_out;

    unsigned short* Kb  = (unsigned short*)d_ws;                 // 2 MB bf16 K
    unsigned short* wbf = Kb + (size_t)BB * HH * LYY * DHH;      // 36864 bf16 weights

    // 1/sqrt(32) * log2(e): exp2-domain softmax, folded into Q only
    const float qscale = 0.17677669529663687f * 1.4426950408889634f;

    hipLaunchKernelGGL(kproj_pre_kernel, dim3(272), dim3(256), 0, stream,
                       y, ipw, ipb, c1w, Kb, wbf);
    hipLaunchKernelGGL(attn_fused_kernel, dim3(LXX / 32, BB), dim3(256), 0, stream,
                       x, Kb, wbf, ipb, c1b, c2w, c2b, gw, gb, out, qscale);
}